// Round 16
// baseline (197.556 us; speedup 1.0000x reference)
//
#include <hip/hip_runtime.h>

// ---------------------------------------------------------------------------
// GIN forward. R16: (1) MLP 32-row strips: LDS 73.8->52.5KB = 3 blocks/CU,
// grid 1563/768-resident = 2.03 waves -> tail waste 25%->1.5%. (2) gather1
// self-term from bf16 xb (L2-hot) instead of streaming 25.6MB fp32 x.
// Gathers (fabric-floored), atomic-free CSR chain, dbuf GEMM cores unchanged.
// ---------------------------------------------------------------------------

typedef __attribute__((ext_vector_type(8))) short bf16x8;
typedef __attribute__((ext_vector_type(4))) float f32x4;

__device__ __forceinline__ float bf2f(unsigned short u) {
  unsigned v = ((unsigned)u) << 16;
  return __builtin_bit_cast(float, v);
}
__device__ __forceinline__ unsigned short f2bf(float f) {
  unsigned u = __builtin_bit_cast(unsigned, f);
  u += 0x7fffu + ((u >> 16) & 1u);
  return (unsigned short)(u >> 16);
}

__device__ __forceinline__ void async16(const void* g, void* l) {
  __builtin_amdgcn_global_load_lds(
      (const __attribute__((address_space(1))) void*)g,
      (__attribute__((address_space(3))) void*)l, 16, 0, 0);
}

static const int NN      = 50000;
static const int NE      = 800000;
static const int NB_E    = 196;            // edge blocks / bins
static const int SCAN_N  = 256 * NB_E;     // 50176
static const int SCAN_NB = 49;             // ceil(50176/1024)
static const int CSR_CAP = 6144;           // per-bin edge cap

// --- fused prep: [0,NB_E) hist blocks | rest: weights + x cast -------------
__global__ __launch_bounds__(256) void k_prep(
    const float* __restrict__ W1a, const float* __restrict__ W1b,
    const float* __restrict__ W2,  const float* __restrict__ W3,
    unsigned short* __restrict__ WT,
    const float* __restrict__ x, unsigned short* __restrict__ xb,
    const int* __restrict__ ei, int* __restrict__ sc)
{
  __shared__ int h[256];
  const int t = threadIdx.x;
  if (blockIdx.x < NB_E) {
    const int k = blockIdx.x;
    h[t] = 0;
    __syncthreads();
    const int4* dv4 = reinterpret_cast<const int4*>(ei + NE);
#pragma unroll
    for (int j = 0; j < 4; j++) {
      int e4 = k * 1024 + j * 256 + t;
      if (e4 < NE / 4) {
        int4 d = dv4[e4];
        atomicAdd(&h[d.x >> 8], 1);
        atomicAdd(&h[d.y >> 8], 1);
        atomicAdd(&h[d.z >> 8], 1);
        atomicAdd(&h[d.w >> 8], 1);
      }
    }
    __syncthreads();
    sc[t * NB_E + k] = h[t];
    return;
  }
  int idx = (blockIdx.x - NB_E) * 256 + t;
  if (idx < 196608) {
    const float* W; unsigned short* out; int K, N, li = idx;
    if (li < 32768)        { W = W1a; out = WT;          K = 128; N = 256; }
    else if (li < 98304)   { W = W1b; out = WT + 32768;  K = 256; N = 256; li -= 32768; }
    else if (li < 163840)  { W = W2;  out = WT + 98304;  K = 256; N = 256; li -= 98304; }
    else                   { W = W3;  out = WT + 163840; K = 256; N = 128; li -= 163840; }
    int n = li / K, k = li - n * K;
    out[li] = f2bf(W[k * N + n]);
  } else if (idx < 196608 + NN * 32) {
    int i = idx - 196608;
    float4 v = reinterpret_cast<const float4*>(x)[i];
    ushort4 b; b.x = f2bf(v.x); b.y = f2bf(v.y); b.z = f2bf(v.z); b.w = f2bf(v.w);
    reinterpret_cast<ushort4*>(xb)[i] = b;
  }
}

// --- scan A: per-block exclusive prefix (in place) + block sums ------------
__global__ __launch_bounds__(1024) void k_scan_a(int* __restrict__ sc,
    int* __restrict__ bsum)
{
  __shared__ int sh[1024];
  const int t = threadIdx.x;
  int idx = blockIdx.x * 1024 + t;
  int c = (idx < SCAN_N) ? sc[idx] : 0;
  sh[t] = c;
  __syncthreads();
  int v = c;
  for (int off = 1; off < 1024; off <<= 1) {
    int tmp = (t >= off) ? sh[t - off] : 0;
    __syncthreads();
    v += tmp; sh[t] = v;
    __syncthreads();
  }
  if (idx < SCAN_N) sc[idx] = v - c;
  if (t == 1023) bsum[blockIdx.x] = v;
}

// --- bin-scatter: deterministic, LDS cursors; inline global base -----------
__global__ __launch_bounds__(256) void k_binscat(const int* __restrict__ ei,
    const int* __restrict__ sc, const int* __restrict__ bsum,
    int* __restrict__ tmp)
{
  __shared__ int base[256];
  __shared__ int cur[256];
  __shared__ int sb[SCAN_NB];
  const int t = threadIdx.x, k = blockIdx.x;
  if (t < SCAN_NB) sb[t] = bsum[t];
  cur[t] = 0;
  __syncthreads();
  {
    int idx = t * NB_E + k;
    int nb = idx >> 10;
    int pre = 0;
    for (int j = 0; j < nb; j++) pre += sb[j];
    base[t] = sc[idx] + pre;
  }
  __syncthreads();
  const int4* sv4 = reinterpret_cast<const int4*>(ei);
  const int4* dv4 = reinterpret_cast<const int4*>(ei + NE);
#pragma unroll
  for (int j = 0; j < 4; j++) {
    int e4 = k * 1024 + j * 256 + t;
    if (e4 < NE / 4) {
      int4 s = sv4[e4];
      int4 d = dv4[e4];
      int b0 = d.x >> 8, p0 = atomicAdd(&cur[b0], 1);
      tmp[base[b0] + p0] = ((d.x & 255) << 16) | s.x;
      int b1 = d.y >> 8, p1 = atomicAdd(&cur[b1], 1);
      tmp[base[b1] + p1] = ((d.y & 255) << 16) | s.y;
      int b2 = d.z >> 8, p2 = atomicAdd(&cur[b2], 1);
      tmp[base[b2] + p2] = ((d.z & 255) << 16) | s.z;
      int b3 = d.w >> 8, p3 = atomicAdd(&cur[b3], 1);
      tmp[base[b3] + p3] = ((d.w & 255) << 16) | s.w;
    }
  }
}

// --- per-bin CSR finish: LDS hist + scan + scatter; inline global base -----
__global__ __launch_bounds__(256) void k_csr(const int* __restrict__ sc,
    const int* __restrict__ bsum, const int* __restrict__ tmp,
    int* __restrict__ offs, int* __restrict__ srcs)
{
  __shared__ int pk[CSR_CAP];
  __shared__ int lh[256];
  __shared__ int lo[256];
  __shared__ int cur[256];
  __shared__ int sb[SCAN_NB];
  const int t = threadIdx.x, b = blockIdx.x;
  if (t < SCAN_NB) sb[t] = bsum[t];
  lh[t] = 0;
  __syncthreads();
  int i0 = b * NB_E, i1 = (b + 1) * NB_E;
  int p0 = 0, p1 = 0;
  for (int j = 0; j < SCAN_NB; j++) {
    p0 += (j < (i0 >> 10)) ? sb[j] : 0;
    p1 += (j < (i1 >> 10)) ? sb[j] : 0;
  }
  int ebeg = sc[i0] + p0;
  int eend = sc[i1] + p1;
  int cnt = eend - ebeg;
  if (cnt > CSR_CAP) cnt = CSR_CAP;
  __syncthreads();
  for (int i = t; i < cnt; i += 256) {
    int v = tmp[ebeg + i];
    pk[i] = v;
    atomicAdd(&lh[(v >> 16) & 255], 1);
  }
  __syncthreads();
  int x = lh[t];
  lo[t] = x;
  __syncthreads();
  for (int off = 1; off < 256; off <<= 1) {
    int y = (t >= off) ? lo[t - off] : 0;
    __syncthreads();
    lo[t] += y;
    __syncthreads();
  }
  int excl = lo[t] - x;
  int g = b * 256 + t;
  if (g <= NN) offs[g] = ebeg + excl;
  cur[t] = excl;
  __syncthreads();
  for (int i = t; i < cnt; i += 256) {
    int v = pk[i];
    int p = atomicAdd(&cur[(v >> 16) & 255], 1);
    srcs[ebeg + p] = v & 0xFFFF;
  }
}

// --- gather-aggregate: 16B/lane, 4-deep unroll (fabric floor) --------------
// out[n] = bf16(scale*feat[n] + sum_{s in N(n)} feat[s]); feat [NN][C] bf16.
// L1: scale = 1+eps (self from bf16 table; one extra rounding, margin ok).
template<int C, bool L1>
__global__ __launch_bounds__(256) void k_gather(const int* __restrict__ offs,
    const int* __restrict__ srcs, const unsigned short* __restrict__ feat,
    const float* __restrict__ eps, unsigned short* __restrict__ out)
{
  constexpr int TPN = C / 8;              // lanes per node (32 or 16)
  int tid = blockIdx.x * 256 + threadIdx.x;
  int node = tid / TPN;
  if (node >= NN) return;
  int c0 = (tid % TPN) * 8;

  float sc_ = 1.0f;
  if (L1) sc_ = 1.0f + eps[0];
  float a[8];
  {
    bf16x8 v = *reinterpret_cast<const bf16x8*>(feat + (size_t)node * C + c0);
#pragma unroll
    for (int j = 0; j < 8; j++) a[j] = bf2f((unsigned short)v[j]) * sc_;
  }

  int beg = __builtin_nontemporal_load(offs + node);
  int end = __builtin_nontemporal_load(offs + node + 1);
  int i = beg;
  for (; i + 4 <= end; i += 4) {
    int s0 = __builtin_nontemporal_load(srcs + i);
    int s1 = __builtin_nontemporal_load(srcs + i + 1);
    int s2 = __builtin_nontemporal_load(srcs + i + 2);
    int s3 = __builtin_nontemporal_load(srcs + i + 3);
    bf16x8 v0 = *reinterpret_cast<const bf16x8*>(feat + (size_t)s0 * C + c0);
    bf16x8 v1 = *reinterpret_cast<const bf16x8*>(feat + (size_t)s1 * C + c0);
    bf16x8 v2 = *reinterpret_cast<const bf16x8*>(feat + (size_t)s2 * C + c0);
    bf16x8 v3 = *reinterpret_cast<const bf16x8*>(feat + (size_t)s3 * C + c0);
#pragma unroll
    for (int j = 0; j < 8; j++) a[j] += bf2f((unsigned short)v0[j]);
#pragma unroll
    for (int j = 0; j < 8; j++) a[j] += bf2f((unsigned short)v1[j]);
#pragma unroll
    for (int j = 0; j < 8; j++) a[j] += bf2f((unsigned short)v2[j]);
#pragma unroll
    for (int j = 0; j < 8; j++) a[j] += bf2f((unsigned short)v3[j]);
  }
  for (; i < end; ++i) {
    int s0 = __builtin_nontemporal_load(srcs + i);
    bf16x8 v0 = *reinterpret_cast<const bf16x8*>(feat + (size_t)s0 * C + c0);
#pragma unroll
    for (int j = 0; j < 8; j++) a[j] += bf2f((unsigned short)v0[j]);
  }

  bf16x8 o;
#pragma unroll
  for (int j = 0; j < 8; j++) o[j] = (short)f2bf(a[j]);
  __builtin_nontemporal_store(o,
      reinterpret_cast<bf16x8*>(out + (size_t)node * C + c0));
}

// --- fused 2-layer MLP on a 32-row strip (3 blocks/CU) ---------------------
// Phase A: H = relu(A[32xCIN] @ B1T^T + bias1) -> LDS [32][264] bf16
// Phase B: out = (H @ B2T^T + bias2), optional relu, bf16 or fp32 out.
// 512 threads = 8 waves. LDS = 4 + 32 + 16.5 = 52.5KB -> 3 blocks/CU.
template<int CIN, int COUT, bool RELU_OUT, bool OUT_F32>
__global__ __launch_bounds__(512) void k_mlp(
    const unsigned short* __restrict__ A,
    const unsigned short* __restrict__ B1T,   // [256][CIN]
    const float* __restrict__ bias1,
    const unsigned short* __restrict__ B2T,   // [COUT][256]
    const float* __restrict__ bias2,
    unsigned short* __restrict__ outB, float* __restrict__ outF, int M)
{
  constexpr int LDH = 264;                // 256 + 8 pad
  __shared__ unsigned short Asb[2][32 * 32];
  __shared__ unsigned short Bsb[2][256 * 32];
  __shared__ unsigned short Hs[32 * LDH];

  const int tid = threadIdx.x;
  const int w = tid >> 6, l = tid & 63;
  const int bm = blockIdx.x * 32;
  const int lr = l >> 2;
  const int lc = (l & 3) * 8;

  auto stageA = [&](int buf, int kt) {
    if (w < 2) {                          // A: 32 rows = 2 chunks
      int tr = w * 16;
      int ar = bm + tr + lr; if (ar >= M) ar = M - 1;
      async16(A + (size_t)ar * CIN + kt + lc, &Asb[buf][tr * 32]);
    }
#pragma unroll
    for (int ch = w; ch < 16; ch += 8) {  // B1: 256 rows
      int tr = ch * 16;
      async16(B1T + (size_t)(tr + lr) * CIN + kt + lc, &Bsb[buf][tr * 32]);
    }
  };
  auto stageB = [&](int buf, int kt) {    // B2: COUT rows
#pragma unroll
    for (int ch = w; ch < COUT / 16; ch += 8) {
      int tr = ch * 16;
      async16(B2T + (size_t)(tr + lr) * 256 + kt + lc, &Bsb[buf][tr * 32]);
    }
  };

  // ---- phase A: 8 waves, each 32 rows x 32 cols (col band w) ----
  f32x4 accA[2][2];
#pragma unroll
  for (int m = 0; m < 2; m++)
#pragma unroll
    for (int n = 0; n < 2; n++) accA[m][n] = (f32x4)(0.0f);

  stageA(0, 0);
  __syncthreads();
  int cur = 0;
  for (int kt = 0; kt < CIN; kt += 32) {
    if (kt + 32 < CIN) stageA(cur ^ 1, kt + 32);
    bf16x8 af[2], bfr[2];
#pragma unroll
    for (int m = 0; m < 2; m++)
      af[m] = *reinterpret_cast<const bf16x8*>(
          &Asb[cur][(m * 16 + (l & 15)) * 32 + (l >> 4) * 8]);
#pragma unroll
    for (int n = 0; n < 2; n++)
      bfr[n] = *reinterpret_cast<const bf16x8*>(
          &Bsb[cur][(w * 32 + n * 16 + (l & 15)) * 32 + (l >> 4) * 8]);
#pragma unroll
    for (int m = 0; m < 2; m++)
#pragma unroll
      for (int n = 0; n < 2; n++)
        accA[m][n] = __builtin_amdgcn_mfma_f32_16x16x32_bf16(
            af[m], bfr[n], accA[m][n], 0, 0, 0);
    __syncthreads();
    cur ^= 1;
  }

  stageB(0, 0);                           // prefetch first B2 slice
#pragma unroll
  for (int m = 0; m < 2; m++) {
    int row0 = m * 16 + ((l >> 4) << 2);
#pragma unroll
    for (int n = 0; n < 2; n++) {
      int col = w * 32 + n * 16 + (l & 15);
      float bv = bias1[col];
#pragma unroll
      for (int r = 0; r < 4; r++) {
        float v = fmaxf(accA[m][n][r] + bv, 0.0f);
        Hs[(row0 + r) * LDH + col] = f2bf(v);
      }
    }
  }
  __syncthreads();

  // ---- phase B: 32 x COUT ----
  constexpr int NWC = COUT / 32;          // col-waves (8 or 4)
  constexpr int NWR = 8 / NWC;            // row-waves (1 or 2)
  constexpr int RPW = 32 / NWR;           // rows per wave (32 or 16)
  constexpr int MF  = RPW / 16;           // m-frags (2 or 1)
  const int wrB = w / NWC, wcB = w % NWC;

  f32x4 accB[MF][2];
#pragma unroll
  for (int m = 0; m < MF; m++)
#pragma unroll
    for (int n = 0; n < 2; n++) accB[m][n] = (f32x4)(0.0f);

  cur = 0;
  for (int kt = 0; kt < 256; kt += 32) {
    if (kt + 32 < 256) stageB(cur ^ 1, kt + 32);
    bf16x8 af[MF], bfr[2];
#pragma unroll
    for (int m = 0; m < MF; m++)
      af[m] = *reinterpret_cast<const bf16x8*>(
          &Hs[(wrB * RPW + m * 16 + (l & 15)) * LDH + kt + (l >> 4) * 8]);
#pragma unroll
    for (int n = 0; n < 2; n++)
      bfr[n] = *reinterpret_cast<const bf16x8*>(
          &Bsb[cur][(wcB * 32 + n * 16 + (l & 15)) * 32 + (l >> 4) * 8]);
#pragma unroll
    for (int m = 0; m < MF; m++)
#pragma unroll
      for (int n = 0; n < 2; n++)
        accB[m][n] = __builtin_amdgcn_mfma_f32_16x16x32_bf16(
            af[m], bfr[n], accB[m][n], 0, 0, 0);
    __syncthreads();
    cur ^= 1;
  }

#pragma unroll
  for (int m = 0; m < MF; m++) {
    int row0 = bm + wrB * RPW + m * 16 + ((l >> 4) << 2);
#pragma unroll
    for (int n = 0; n < 2; n++) {
      int col = wcB * 32 + n * 16 + (l & 15);
      float bv = bias2[col];
#pragma unroll
      for (int r = 0; r < 4; r++) {
        int row = row0 + r;
        if (row < M) {
          float v = accB[m][n][r] + bv;
          if (RELU_OUT) v = fmaxf(v, 0.0f);
          if (OUT_F32) outF[(size_t)row * COUT + col] = v;
          else         outB[(size_t)row * COUT + col] = f2bf(v);
        }
      }
    }
  }
}

// ---------------------------------------------------------------------------
// workspace layout (bytes):
//  xb   [ 0.0 .. 12.8M)  bf16 x     (prep -> gather1)
//  z1b  [12.8 .. 25.6M)  bf16 z1    (gather1 -> mlp1)
//  hb   [25.6 .. 51.2M)  bf16 h     (mlp1 -> gather2)
//  z2b  [51.2 .. 76.8M)  bf16 z2    (gather2 -> mlp2)
//  sc   [76.8M ..)       int[50176]
//  bsum [+200704]        int[64]
//  tmp  [77.001M ..)     int[800000]
//  srcs [80.2M ..)       int[800000]
//  offs [83.4M ..)       int[50001]
//  WT   [83.7M ..)       bf16 weights (393216 B)
static const size_t OFF_XB   = 0;
static const size_t OFF_Z1B  = 12800000;
static const size_t OFF_HB   = 25600000;
static const size_t OFF_Z2B  = 51200000;
static const size_t OFF_SC   = 76800000;
static const size_t OFF_BSUM = 77000704;
static const size_t OFF_TMP  = 77000960;
static const size_t OFF_SRC  = 80200960;
static const size_t OFF_OFFS = 83400960;
static const size_t OFF_WT   = 83601024;

extern "C" void kernel_launch(void* const* d_in, const int* in_sizes, int n_in,
                              void* d_out, int out_size, void* d_ws, size_t ws_size,
                              hipStream_t stream)
{
  const float* x    = (const float*)d_in[0];
  const int*   ei   = (const int*)d_in[1];
  const float* W1a  = (const float*)d_in[2];
  const float* b1a  = (const float*)d_in[3];
  const float* W1b  = (const float*)d_in[4];
  const float* b1b  = (const float*)d_in[5];
  const float* eps1 = (const float*)d_in[6];
  const float* W2   = (const float*)d_in[7];
  const float* b2   = (const float*)d_in[8];
  const float* W3   = (const float*)d_in[9];
  const float* b3   = (const float*)d_in[10];

  char* ws = (char*)d_ws;
  unsigned short* xb   = (unsigned short*)(ws + OFF_XB);
  unsigned short* z1b  = (unsigned short*)(ws + OFF_Z1B);
  unsigned short* hb   = (unsigned short*)(ws + OFF_HB);
  unsigned short* z2b  = (unsigned short*)(ws + OFF_Z2B);
  int*            sc   = (int*)(ws + OFF_SC);
  int*            bsum = (int*)(ws + OFF_BSUM);
  int*            tmp  = (int*)(ws + OFF_TMP);
  int*            srcs = (int*)(ws + OFF_SRC);
  int*            offs = (int*)(ws + OFF_OFFS);
  unsigned short* wt   = (unsigned short*)(ws + OFF_WT);
  unsigned short* w1at = wt;                 // [256][128]
  unsigned short* w1bt = wt + 32768;         // [256][256]
  unsigned short* w2t  = wt + 98304;         // [256][256]
  unsigned short* w3t  = wt + 163840;        // [128][256]

  // prep (hist blocks first, then weights + x->bf16), then CSR chain
  k_prep<<<NB_E + (196608 + NN * 32 + 255) / 256, 256, 0, stream>>>(
      W1a, W1b, W2, W3, wt, x, xb, ei, sc);
  k_scan_a<<<SCAN_NB, 1024, 0, stream>>>(sc, bsum);
  k_binscat<<<NB_E, 256, 0, stream>>>(ei, sc, bsum, tmp);
  k_csr<<<NB_E, 256, 0, stream>>>(sc, bsum, tmp, offs, srcs);

  // layer 1: gather1 -> z1; mlp1 (z1 -> h1 -> h)
  k_gather<128, true><<<NN * 16 / 256, 256, 0, stream>>>(
      offs, srcs, xb, eps1, z1b);
  k_mlp<128, 256, true, false><<<(NN + 31) / 32, 512, 0, stream>>>(
      z1b, w1at, b1a, w1bt, b1b, hb, nullptr, NN);

  // layer 2: gather2 -> z2; mlp2 (z2 -> h2 -> out)
  k_gather<256, false><<<NN * 32 / 256, 256, 0, stream>>>(
      offs, srcs, hb, nullptr, z2b);
  k_mlp<256, 128, false, true><<<(NN + 31) / 32, 512, 0, stream>>>(
      z2b, w2t, b2, w3t, b3, nullptr, (float*)d_out, NN);
}

// Round 17
// 188.234 us; speedup vs baseline: 1.0495x; 1.0495x over previous
//
#include <hip/hip_runtime.h>

// ---------------------------------------------------------------------------
// GIN forward. R17: best-of R15+R16. R16's 32-row MLP strips regressed
// (B-staging traffic doubled; MLP is staging-bound not tail-bound) -> revert
// to R15's 64-row strips (2 blocks/CU). Keep R16's bf16-self gather1 (drops
// the 25.6MB fp32 x stream). Atomic-free CSR chain unchanged.
// ---------------------------------------------------------------------------

typedef __attribute__((ext_vector_type(8))) short bf16x8;
typedef __attribute__((ext_vector_type(4))) float f32x4;

__device__ __forceinline__ float bf2f(unsigned short u) {
  unsigned v = ((unsigned)u) << 16;
  return __builtin_bit_cast(float, v);
}
__device__ __forceinline__ unsigned short f2bf(float f) {
  unsigned u = __builtin_bit_cast(unsigned, f);
  u += 0x7fffu + ((u >> 16) & 1u);
  return (unsigned short)(u >> 16);
}

__device__ __forceinline__ void async16(const void* g, void* l) {
  __builtin_amdgcn_global_load_lds(
      (const __attribute__((address_space(1))) void*)g,
      (__attribute__((address_space(3))) void*)l, 16, 0, 0);
}

static const int NN      = 50000;
static const int NE      = 800000;
static const int NB_E    = 196;            // edge blocks / bins
static const int SCAN_N  = 256 * NB_E;     // 50176
static const int SCAN_NB = 49;             // ceil(50176/1024)
static const int CSR_CAP = 6144;           // per-bin edge cap

// --- fused prep: [0,NB_E) hist blocks | rest: weights + x cast -------------
__global__ __launch_bounds__(256) void k_prep(
    const float* __restrict__ W1a, const float* __restrict__ W1b,
    const float* __restrict__ W2,  const float* __restrict__ W3,
    unsigned short* __restrict__ WT,
    const float* __restrict__ x, unsigned short* __restrict__ xb,
    const int* __restrict__ ei, int* __restrict__ sc)
{
  __shared__ int h[256];
  const int t = threadIdx.x;
  if (blockIdx.x < NB_E) {
    const int k = blockIdx.x;
    h[t] = 0;
    __syncthreads();
    const int4* dv4 = reinterpret_cast<const int4*>(ei + NE);
#pragma unroll
    for (int j = 0; j < 4; j++) {
      int e4 = k * 1024 + j * 256 + t;
      if (e4 < NE / 4) {
        int4 d = dv4[e4];
        atomicAdd(&h[d.x >> 8], 1);
        atomicAdd(&h[d.y >> 8], 1);
        atomicAdd(&h[d.z >> 8], 1);
        atomicAdd(&h[d.w >> 8], 1);
      }
    }
    __syncthreads();
    sc[t * NB_E + k] = h[t];
    return;
  }
  int idx = (blockIdx.x - NB_E) * 256 + t;
  if (idx < 196608) {
    const float* W; unsigned short* out; int K, N, li = idx;
    if (li < 32768)        { W = W1a; out = WT;          K = 128; N = 256; }
    else if (li < 98304)   { W = W1b; out = WT + 32768;  K = 256; N = 256; li -= 32768; }
    else if (li < 163840)  { W = W2;  out = WT + 98304;  K = 256; N = 256; li -= 98304; }
    else                   { W = W3;  out = WT + 163840; K = 256; N = 128; li -= 163840; }
    int n = li / K, k = li - n * K;
    out[li] = f2bf(W[k * N + n]);
  } else if (idx < 196608 + NN * 32) {
    int i = idx - 196608;
    float4 v = reinterpret_cast<const float4*>(x)[i];
    ushort4 b; b.x = f2bf(v.x); b.y = f2bf(v.y); b.z = f2bf(v.z); b.w = f2bf(v.w);
    reinterpret_cast<ushort4*>(xb)[i] = b;
  }
}

// --- scan A: per-block exclusive prefix (in place) + block sums ------------
__global__ __launch_bounds__(1024) void k_scan_a(int* __restrict__ sc,
    int* __restrict__ bsum)
{
  __shared__ int sh[1024];
  const int t = threadIdx.x;
  int idx = blockIdx.x * 1024 + t;
  int c = (idx < SCAN_N) ? sc[idx] : 0;
  sh[t] = c;
  __syncthreads();
  int v = c;
  for (int off = 1; off < 1024; off <<= 1) {
    int tmp = (t >= off) ? sh[t - off] : 0;
    __syncthreads();
    v += tmp; sh[t] = v;
    __syncthreads();
  }
  if (idx < SCAN_N) sc[idx] = v - c;
  if (t == 1023) bsum[blockIdx.x] = v;
}

// --- bin-scatter: deterministic, LDS cursors; inline global base -----------
__global__ __launch_bounds__(256) void k_binscat(const int* __restrict__ ei,
    const int* __restrict__ sc, const int* __restrict__ bsum,
    int* __restrict__ tmp)
{
  __shared__ int base[256];
  __shared__ int cur[256];
  __shared__ int sb[SCAN_NB];
  const int t = threadIdx.x, k = blockIdx.x;
  if (t < SCAN_NB) sb[t] = bsum[t];
  cur[t] = 0;
  __syncthreads();
  {
    int idx = t * NB_E + k;
    int nb = idx >> 10;
    int pre = 0;
    for (int j = 0; j < nb; j++) pre += sb[j];
    base[t] = sc[idx] + pre;
  }
  __syncthreads();
  const int4* sv4 = reinterpret_cast<const int4*>(ei);
  const int4* dv4 = reinterpret_cast<const int4*>(ei + NE);
#pragma unroll
  for (int j = 0; j < 4; j++) {
    int e4 = k * 1024 + j * 256 + t;
    if (e4 < NE / 4) {
      int4 s = sv4[e4];
      int4 d = dv4[e4];
      int b0 = d.x >> 8, p0 = atomicAdd(&cur[b0], 1);
      tmp[base[b0] + p0] = ((d.x & 255) << 16) | s.x;
      int b1 = d.y >> 8, p1 = atomicAdd(&cur[b1], 1);
      tmp[base[b1] + p1] = ((d.y & 255) << 16) | s.y;
      int b2 = d.z >> 8, p2 = atomicAdd(&cur[b2], 1);
      tmp[base[b2] + p2] = ((d.z & 255) << 16) | s.z;
      int b3 = d.w >> 8, p3 = atomicAdd(&cur[b3], 1);
      tmp[base[b3] + p3] = ((d.w & 255) << 16) | s.w;
    }
  }
}

// --- per-bin CSR finish: LDS hist + scan + scatter; inline global base -----
__global__ __launch_bounds__(256) void k_csr(const int* __restrict__ sc,
    const int* __restrict__ bsum, const int* __restrict__ tmp,
    int* __restrict__ offs, int* __restrict__ srcs)
{
  __shared__ int pk[CSR_CAP];
  __shared__ int lh[256];
  __shared__ int lo[256];
  __shared__ int cur[256];
  __shared__ int sb[SCAN_NB];
  const int t = threadIdx.x, b = blockIdx.x;
  if (t < SCAN_NB) sb[t] = bsum[t];
  lh[t] = 0;
  __syncthreads();
  int i0 = b * NB_E, i1 = (b + 1) * NB_E;
  int p0 = 0, p1 = 0;
  for (int j = 0; j < SCAN_NB; j++) {
    p0 += (j < (i0 >> 10)) ? sb[j] : 0;
    p1 += (j < (i1 >> 10)) ? sb[j] : 0;
  }
  int ebeg = sc[i0] + p0;
  int eend = sc[i1] + p1;
  int cnt = eend - ebeg;
  if (cnt > CSR_CAP) cnt = CSR_CAP;
  __syncthreads();
  for (int i = t; i < cnt; i += 256) {
    int v = tmp[ebeg + i];
    pk[i] = v;
    atomicAdd(&lh[(v >> 16) & 255], 1);
  }
  __syncthreads();
  int x = lh[t];
  lo[t] = x;
  __syncthreads();
  for (int off = 1; off < 256; off <<= 1) {
    int y = (t >= off) ? lo[t - off] : 0;
    __syncthreads();
    lo[t] += y;
    __syncthreads();
  }
  int excl = lo[t] - x;
  int g = b * 256 + t;
  if (g <= NN) offs[g] = ebeg + excl;
  cur[t] = excl;
  __syncthreads();
  for (int i = t; i < cnt; i += 256) {
    int v = pk[i];
    int p = atomicAdd(&cur[(v >> 16) & 255], 1);
    srcs[ebeg + p] = v & 0xFFFF;
  }
}

// --- gather-aggregate: 16B/lane, 4-deep unroll (fabric floor) --------------
// out[n] = bf16(scale*feat[n] + sum_{s in N(n)} feat[s]); feat [NN][C] bf16.
// L1: scale = 1+eps (self from bf16 table).
template<int C, bool L1>
__global__ __launch_bounds__(256) void k_gather(const int* __restrict__ offs,
    const int* __restrict__ srcs, const unsigned short* __restrict__ feat,
    const float* __restrict__ eps, unsigned short* __restrict__ out)
{
  constexpr int TPN = C / 8;              // lanes per node (32 or 16)
  int tid = blockIdx.x * 256 + threadIdx.x;
  int node = tid / TPN;
  if (node >= NN) return;
  int c0 = (tid % TPN) * 8;

  float sc_ = 1.0f;
  if (L1) sc_ = 1.0f + eps[0];
  float a[8];
  {
    bf16x8 v = *reinterpret_cast<const bf16x8*>(feat + (size_t)node * C + c0);
#pragma unroll
    for (int j = 0; j < 8; j++) a[j] = bf2f((unsigned short)v[j]) * sc_;
  }

  int beg = __builtin_nontemporal_load(offs + node);
  int end = __builtin_nontemporal_load(offs + node + 1);
  int i = beg;
  for (; i + 4 <= end; i += 4) {
    int s0 = __builtin_nontemporal_load(srcs + i);
    int s1 = __builtin_nontemporal_load(srcs + i + 1);
    int s2 = __builtin_nontemporal_load(srcs + i + 2);
    int s3 = __builtin_nontemporal_load(srcs + i + 3);
    bf16x8 v0 = *reinterpret_cast<const bf16x8*>(feat + (size_t)s0 * C + c0);
    bf16x8 v1 = *reinterpret_cast<const bf16x8*>(feat + (size_t)s1 * C + c0);
    bf16x8 v2 = *reinterpret_cast<const bf16x8*>(feat + (size_t)s2 * C + c0);
    bf16x8 v3 = *reinterpret_cast<const bf16x8*>(feat + (size_t)s3 * C + c0);
#pragma unroll
    for (int j = 0; j < 8; j++) a[j] += bf2f((unsigned short)v0[j]);
#pragma unroll
    for (int j = 0; j < 8; j++) a[j] += bf2f((unsigned short)v1[j]);
#pragma unroll
    for (int j = 0; j < 8; j++) a[j] += bf2f((unsigned short)v2[j]);
#pragma unroll
    for (int j = 0; j < 8; j++) a[j] += bf2f((unsigned short)v3[j]);
  }
  for (; i < end; ++i) {
    int s0 = __builtin_nontemporal_load(srcs + i);
    bf16x8 v0 = *reinterpret_cast<const bf16x8*>(feat + (size_t)s0 * C + c0);
#pragma unroll
    for (int j = 0; j < 8; j++) a[j] += bf2f((unsigned short)v0[j]);
  }

  bf16x8 o;
#pragma unroll
  for (int j = 0; j < 8; j++) o[j] = (short)f2bf(a[j]);
  __builtin_nontemporal_store(o,
      reinterpret_cast<bf16x8*>(out + (size_t)node * C + c0));
}

// --- fused 2-layer MLP on a 64-row strip (R15, 2 blocks/CU) ----------------
// Phase A: H = relu(A[64xCIN] @ B1T^T + bias1) -> LDS [64][264] bf16
// Phase B: out = (H @ B2T^T + bias2), optional relu, bf16 or fp32 out.
// 512 threads = 8 waves. LDS = 8 + 32 + 33 = 73.8KB -> 2 blocks/CU.
template<int CIN, int COUT, bool RELU_OUT, bool OUT_F32>
__global__ __launch_bounds__(512) void k_mlp(
    const unsigned short* __restrict__ A,
    const unsigned short* __restrict__ B1T,   // [256][CIN]
    const float* __restrict__ bias1,
    const unsigned short* __restrict__ B2T,   // [COUT][256]
    const float* __restrict__ bias2,
    unsigned short* __restrict__ outB, float* __restrict__ outF, int M)
{
  constexpr int LDH = 264;                // 256 + 8 pad
  __shared__ unsigned short Asb[2][64 * 32];
  __shared__ unsigned short Bsb[2][256 * 32];
  __shared__ unsigned short Hs[64 * LDH];

  const int tid = threadIdx.x;
  const int w = tid >> 6, l = tid & 63;
  const int bm = blockIdx.x * 64;
  const int lr = l >> 2;
  const int lc = (l & 3) * 8;

  auto stageA = [&](int buf, int kt) {
    if (w < 4) {                          // A: 64 rows = 4 chunks
      int tr = w * 16;
      int ar = bm + tr + lr; if (ar >= M) ar = M - 1;
      async16(A + (size_t)ar * CIN + kt + lc, &Asb[buf][tr * 32]);
    }
#pragma unroll
    for (int ch = w; ch < 16; ch += 8) {  // B1: 256 rows
      int tr = ch * 16;
      async16(B1T + (size_t)(tr + lr) * CIN + kt + lc, &Bsb[buf][tr * 32]);
    }
  };
  auto stageB = [&](int buf, int kt) {    // B2: COUT rows
#pragma unroll
    for (int ch = w; ch < COUT / 16; ch += 8) {
      int tr = ch * 16;
      async16(B2T + (size_t)(tr + lr) * 256 + kt + lc, &Bsb[buf][tr * 32]);
    }
  };

  // ---- phase A: 8 waves, each 64 rows x 32 cols (col band w) ----
  f32x4 accA[4][2];
#pragma unroll
  for (int m = 0; m < 4; m++)
#pragma unroll
    for (int n = 0; n < 2; n++) accA[m][n] = (f32x4)(0.0f);

  stageA(0, 0);
  __syncthreads();
  int cur = 0;
  for (int kt = 0; kt < CIN; kt += 32) {
    if (kt + 32 < CIN) stageA(cur ^ 1, kt + 32);
    bf16x8 af[4], bfr[2];
#pragma unroll
    for (int m = 0; m < 4; m++)
      af[m] = *reinterpret_cast<const bf16x8*>(
          &Asb[cur][(m * 16 + (l & 15)) * 32 + (l >> 4) * 8]);
#pragma unroll
    for (int n = 0; n < 2; n++)
      bfr[n] = *reinterpret_cast<const bf16x8*>(
          &Bsb[cur][(w * 32 + n * 16 + (l & 15)) * 32 + (l >> 4) * 8]);
#pragma unroll
    for (int m = 0; m < 4; m++)
#pragma unroll
      for (int n = 0; n < 2; n++)
        accA[m][n] = __builtin_amdgcn_mfma_f32_16x16x32_bf16(
            af[m], bfr[n], accA[m][n], 0, 0, 0);
    __syncthreads();
    cur ^= 1;
  }

  stageB(0, 0);                           // prefetch first B2 slice
#pragma unroll
  for (int m = 0; m < 4; m++) {
    int row0 = m * 16 + ((l >> 4) << 2);
#pragma unroll
    for (int n = 0; n < 2; n++) {
      int col = w * 32 + n * 16 + (l & 15);
      float bv = bias1[col];
#pragma unroll
      for (int r = 0; r < 4; r++) {
        float v = fmaxf(accA[m][n][r] + bv, 0.0f);
        Hs[(row0 + r) * LDH + col] = f2bf(v);
      }
    }
  }
  __syncthreads();

  // ---- phase B: 64 x COUT ----
  constexpr int NWC = COUT / 32;          // col-waves (8 or 4)
  constexpr int NWR = 8 / NWC;            // row-waves (1 or 2)
  constexpr int RPW = 64 / NWR;           // rows per wave (64 or 32)
  constexpr int MF  = RPW / 16;           // m-frags (4 or 2)
  const int wrB = w / NWC, wcB = w % NWC;

  f32x4 accB[MF][2];
#pragma unroll
  for (int m = 0; m < MF; m++)
#pragma unroll
    for (int n = 0; n < 2; n++) accB[m][n] = (f32x4)(0.0f);

  cur = 0;
  for (int kt = 0; kt < 256; kt += 32) {
    if (kt + 32 < 256) stageB(cur ^ 1, kt + 32);
    bf16x8 af[MF], bfr[2];
#pragma unroll
    for (int m = 0; m < MF; m++)
      af[m] = *reinterpret_cast<const bf16x8*>(
          &Hs[(wrB * RPW + m * 16 + (l & 15)) * LDH + kt + (l >> 4) * 8]);
#pragma unroll
    for (int n = 0; n < 2; n++)
      bfr[n] = *reinterpret_cast<const bf16x8*>(
          &Bsb[cur][(wcB * 32 + n * 16 + (l & 15)) * 32 + (l >> 4) * 8]);
#pragma unroll
    for (int m = 0; m < MF; m++)
#pragma unroll
      for (int n = 0; n < 2; n++)
        accB[m][n] = __builtin_amdgcn_mfma_f32_16x16x32_bf16(
            af[m], bfr[n], accB[m][n], 0, 0, 0);
    __syncthreads();
    cur ^= 1;
  }

#pragma unroll
  for (int m = 0; m < MF; m++) {
    int row0 = bm + wrB * RPW + m * 16 + ((l >> 4) << 2);
#pragma unroll
    for (int n = 0; n < 2; n++) {
      int col = wcB * 32 + n * 16 + (l & 15);
      float bv = bias2[col];
#pragma unroll
      for (int r = 0; r < 4; r++) {
        int row = row0 + r;
        if (row < M) {
          float v = accB[m][n][r] + bv;
          if (RELU_OUT) v = fmaxf(v, 0.0f);
          if (OUT_F32) outF[(size_t)row * COUT + col] = v;
          else         outB[(size_t)row * COUT + col] = f2bf(v);
        }
      }
    }
  }
}

// ---------------------------------------------------------------------------
// workspace layout (bytes):
//  xb   [ 0.0 .. 12.8M)  bf16 x     (prep -> gather1)
//  z1b  [12.8 .. 25.6M)  bf16 z1    (gather1 -> mlp1)
//  hb   [25.6 .. 51.2M)  bf16 h     (mlp1 -> gather2)
//  z2b  [51.2 .. 76.8M)  bf16 z2    (gather2 -> mlp2)
//  sc   [76.8M ..)       int[50176]
//  bsum [+200704]        int[64]
//  tmp  [77.001M ..)     int[800000]
//  srcs [80.2M ..)       int[800000]
//  offs [83.4M ..)       int[50001]
//  WT   [83.7M ..)       bf16 weights (393216 B)
static const size_t OFF_XB   = 0;
static const size_t OFF_Z1B  = 12800000;
static const size_t OFF_HB   = 25600000;
static const size_t OFF_Z2B  = 51200000;
static const size_t OFF_SC   = 76800000;
static const size_t OFF_BSUM = 77000704;
static const size_t OFF_TMP  = 77000960;
static const size_t OFF_SRC  = 80200960;
static const size_t OFF_OFFS = 83400960;
static const size_t OFF_WT   = 83601024;

extern "C" void kernel_launch(void* const* d_in, const int* in_sizes, int n_in,
                              void* d_out, int out_size, void* d_ws, size_t ws_size,
                              hipStream_t stream)
{
  const float* x    = (const float*)d_in[0];
  const int*   ei   = (const int*)d_in[1];
  const float* W1a  = (const float*)d_in[2];
  const float* b1a  = (const float*)d_in[3];
  const float* W1b  = (const float*)d_in[4];
  const float* b1b  = (const float*)d_in[5];
  const float* eps1 = (const float*)d_in[6];
  const float* W2   = (const float*)d_in[7];
  const float* b2   = (const float*)d_in[8];
  const float* W3   = (const float*)d_in[9];
  const float* b3   = (const float*)d_in[10];

  char* ws = (char*)d_ws;
  unsigned short* xb   = (unsigned short*)(ws + OFF_XB);
  unsigned short* z1b  = (unsigned short*)(ws + OFF_Z1B);
  unsigned short* hb   = (unsigned short*)(ws + OFF_HB);
  unsigned short* z2b  = (unsigned short*)(ws + OFF_Z2B);
  int*            sc   = (int*)(ws + OFF_SC);
  int*            bsum = (int*)(ws + OFF_BSUM);
  int*            tmp  = (int*)(ws + OFF_TMP);
  int*            srcs = (int*)(ws + OFF_SRC);
  int*            offs = (int*)(ws + OFF_OFFS);
  unsigned short* wt   = (unsigned short*)(ws + OFF_WT);
  unsigned short* w1at = wt;                 // [256][128]
  unsigned short* w1bt = wt + 32768;         // [256][256]
  unsigned short* w2t  = wt + 98304;         // [256][256]
  unsigned short* w3t  = wt + 163840;        // [128][256]

  // prep (hist blocks first, then weights + x->bf16), then CSR chain
  k_prep<<<NB_E + (196608 + NN * 32 + 255) / 256, 256, 0, stream>>>(
      W1a, W1b, W2, W3, wt, x, xb, ei, sc);
  k_scan_a<<<SCAN_NB, 1024, 0, stream>>>(sc, bsum);
  k_binscat<<<NB_E, 256, 0, stream>>>(ei, sc, bsum, tmp);
  k_csr<<<NB_E, 256, 0, stream>>>(sc, bsum, tmp, offs, srcs);

  // layer 1: gather1 -> z1; mlp1 (z1 -> h1 -> h)
  k_gather<128, true><<<NN * 16 / 256, 256, 0, stream>>>(
      offs, srcs, xb, eps1, z1b);
  k_mlp<128, 256, true, false><<<(NN + 63) / 64, 512, 0, stream>>>(
      z1b, w1at, b1a, w1bt, b1b, hb, nullptr, NN);

  // layer 2: gather2 -> z2; mlp2 (z2 -> h2 -> out)
  k_gather<256, false><<<NN * 32 / 256, 256, 0, stream>>>(
      offs, srcs, hb, nullptr, z2b);
  k_mlp<256, 128, false, true><<<(NN + 63) / 64, 512, 0, stream>>>(
      z2b, w2t, b2, w3t, b3, nullptr, (float*)d_out, NN);
}